// Round 1
// baseline (109.782 us; speedup 1.0000x reference)
//
#include <hip/hip_runtime.h>

#define NROWS 4096
#define NCOLS 6144

// Per-element classification:
//   row % 3 == 0 -> contributes |sigmoid(p)-t| to r_sum   (1366 rows)
//   row % 3 == 1 -> contributes |sigmoid(p)-t| to t_sum   (1365 rows)
//   (col % 3 == 2 && col < 4096) -> contributes circular dist to p_sum (all rows)
// Final: r/(1366*6144), t/(1365*6144), phi/(4096*2048).

__global__ void __launch_bounds__(256)
spherical_main(const float* __restrict__ preds,
               const float* __restrict__ targs,
               double* __restrict__ acc) {
    const int total4 = NROWS * NCOLS / 4;
    float sr = 0.f, st = 0.f, sp = 0.f;

    for (int i4 = blockIdx.x * blockDim.x + threadIdx.x; i4 < total4;
         i4 += gridDim.x * blockDim.x) {
        const int e    = i4 * 4;            // flat element index (float4-aligned)
        const int row  = e / NCOLS;         // compiler emits magic-mul
        const int col0 = e - row * NCOLS;   // 6144 % 4 == 0: float4 never crosses a row
        const int rm   = row % 3;

        const float4 p4 = reinterpret_cast<const float4*>(preds)[i4];
        const float4 t4 = reinterpret_cast<const float4*>(targs)[i4];
        const float ps[4] = {p4.x, p4.y, p4.z, p4.w};
        const float ts[4] = {t4.x, t4.y, t4.z, t4.w};

        int cm = col0 % 3;
#pragma unroll
        for (int j = 0; j < 4; ++j) {
            const float s = 1.0f / (1.0f + __expf(-ps[j]));
            const float x = s - ts[j];
            const float a = fabsf(x);
            if (rm == 0)      sr += a;
            else if (rm == 1) st += a;
            const int c = col0 + j;
            if (cm == 2 && c < 4096) {
                // circular distance: min(|x|, |x-1|, |x+1|)
                sp += fminf(a, fminf(fabsf(x - 1.0f), fabsf(x + 1.0f)));
            }
            cm = (cm == 2) ? 0 : cm + 1;
        }
    }

    // 64-lane wave reduction
#pragma unroll
    for (int off = 32; off > 0; off >>= 1) {
        sr += __shfl_down(sr, off);
        st += __shfl_down(st, off);
        sp += __shfl_down(sp, off);
    }

    __shared__ float lr[4], lt[4], lp[4];
    const int wave = threadIdx.x >> 6;
    const int lane = threadIdx.x & 63;
    if (lane == 0) { lr[wave] = sr; lt[wave] = st; lp[wave] = sp; }
    __syncthreads();

    if (threadIdx.x == 0) {
        float br = 0.f, bt = 0.f, bp = 0.f;
#pragma unroll
        for (int w = 0; w < 4; ++w) { br += lr[w]; bt += lt[w]; bp += lp[w]; }
        atomicAdd(&acc[0], (double)br);
        atomicAdd(&acc[1], (double)bt);
        atomicAdd(&acc[2], (double)bp);
    }
}

__global__ void spherical_final(const double* __restrict__ acc,
                                float* __restrict__ out) {
    const double r = acc[0] / (1366.0 * 6144.0);
    const double t = acc[1] / (1365.0 * 6144.0);
    const double p = acc[2] / (4096.0 * 2048.0);
    out[0] = (float)(r + t + p);
    out[1] = (float)r;
    out[2] = (float)t;
    out[3] = (float)p;
}

extern "C" void kernel_launch(void* const* d_in, const int* in_sizes, int n_in,
                              void* d_out, int out_size, void* d_ws, size_t ws_size,
                              hipStream_t stream) {
    const float* preds = (const float*)d_in[0];
    const float* targs = (const float*)d_in[1];
    double* acc = (double*)d_ws;

    hipMemsetAsync(acc, 0, 3 * sizeof(double), stream);  // graph-capture safe

    dim3 block(256);
    dim3 grid(2048);  // 8 blocks/CU on 256 CUs; grid-stride covers 6.29M float4
    spherical_main<<<grid, block, 0, stream>>>(preds, targs, acc);
    spherical_final<<<1, 1, 0, stream>>>(acc, (float*)d_out);
}

// Round 2
// 103.723 us; speedup vs baseline: 1.0584x; 1.0584x over previous
//
#include <hip/hip_runtime.h>

#define NROWS 4096
#define NCOLS 6144
#define CHUNKS 6   // (NCOLS/4) float4 per row / 256 threads = 1536/256

// Semantics (verbatim from reference):
//   r_loss  = mean |sigmoid(p)-t| over rows ≡0 mod 3  (1366 rows × 6144 cols)
//   t_loss  = mean |sigmoid(p)-t| over rows ≡1 mod 3  (1365 rows × 6144 cols)
//   phi     = sum of circular dist over ALL rows, cols in {2,5,..,4094}
//             (col%3==2 AND col<4096 — b=4096 used as the column bound!),
//             divided by 4096*2048.

__global__ void __launch_bounds__(256)
spherical_main(const float4* __restrict__ preds,
               const float4* __restrict__ targs,
               double* __restrict__ acc) {
    const int row = blockIdx.x;          // one row per block
    const int rm  = row % 3;             // wave-uniform
    const float4* prow = preds + row * (NCOLS / 4);
    const float4* trow = targs + row * (NCOLS / 4);

    // Batch ALL loads up front: 12 independent dwordx4 in flight per thread.
    float4 p[CHUNKS], t[CHUNKS];
#pragma unroll
    for (int k = 0; k < CHUNKS; ++k) p[k] = prow[threadIdx.x + 256 * k];
#pragma unroll
    for (int k = 0; k < CHUNKS; ++k) t[k] = trow[threadIdx.x + 256 * k];

    float asum = 0.f, psum = 0.f;
#pragma unroll
    for (int k = 0; k < CHUNKS; ++k) {
        const int c = threadIdx.x + 256 * k;   // float4 index in row; col0 = 4*c
        const float ps[4] = {p[k].x, p[k].y, p[k].z, p[k].w};
        const float ts[4] = {t[k].x, t[k].y, t[k].z, t[k].w};
#pragma unroll
        for (int j = 0; j < 4; ++j) {
            const float s = 1.0f / (1.0f + __expf(-ps[j]));
            const float x = s - ts[j];
            const float a = fabsf(x);
            asum += a;                         // used only if rm==0 or rm==1
            if (k < 4) {                       // cols 4c+j < 4096 iff k<4 (compile-time)
                const float d = fminf(a, fminf(fabsf(x - 1.f), fabsf(x + 1.f)));
                psum += (((c + j) % 3) == 2) ? d : 0.f;   // predicated, no branch
            }
        }
    }

    // 64-lane wave reduction of both partials
#pragma unroll
    for (int off = 32; off > 0; off >>= 1) {
        asum += __shfl_down(asum, off);
        psum += __shfl_down(psum, off);
    }

    __shared__ float la[4], lp_[4];
    const int wave = threadIdx.x >> 6;
    const int lane = threadIdx.x & 63;
    if (lane == 0) { la[wave] = asum; lp_[wave] = psum; }
    __syncthreads();

    if (threadIdx.x == 0) {
        float ba = la[0] + la[1] + la[2] + la[3];
        float bp = lp_[0] + lp_[1] + lp_[2] + lp_[3];
        atomicAdd(&acc[2], (double)bp);
        if (rm == 0)      atomicAdd(&acc[0], (double)ba);
        else if (rm == 1) atomicAdd(&acc[1], (double)ba);
    }
}

__global__ void spherical_final(const double* __restrict__ acc,
                                float* __restrict__ out) {
    const double r = acc[0] / (1366.0 * 6144.0);
    const double t = acc[1] / (1365.0 * 6144.0);
    const double p = acc[2] / (4096.0 * 2048.0);
    out[0] = (float)(r + t + p);
    out[1] = (float)r;
    out[2] = (float)t;
    out[3] = (float)p;
}

extern "C" void kernel_launch(void* const* d_in, const int* in_sizes, int n_in,
                              void* d_out, int out_size, void* d_ws, size_t ws_size,
                              hipStream_t stream) {
    const float4* preds = (const float4*)d_in[0];
    const float4* targs = (const float4*)d_in[1];
    double* acc = (double*)d_ws;

    hipMemsetAsync(acc, 0, 3 * sizeof(double), stream);  // graph-capture safe

    spherical_main<<<dim3(NROWS), dim3(256), 0, stream>>>(preds, targs, acc);
    spherical_final<<<1, 1, 0, stream>>>(acc, (float*)d_out);
}

// Round 3
// 38.062 us; speedup vs baseline: 2.8843x; 2.7251x over previous
//
#include <hip/hip_runtime.h>

#define NROWS 4096
#define NCOLS 6144
#define TPB   256
#define CHUNKS 6   // 1536 float4 per row / 256 threads

// Semantics (verbatim from reference):
//   r_loss  = mean |sigmoid(p)-t| over rows ≡0 mod 3  (1366 rows × 6144 cols)
//   t_loss  = mean |sigmoid(p)-t| over rows ≡1 mod 3  (1365 rows × 6144 cols)
//   phi     = sum of circular dist over ALL rows, cols with col%3==2 AND col<4096
//             (b=4096 used as the column bound!), divided by 4096*2048.

__global__ void __launch_bounds__(256)
spherical_main(const float4* __restrict__ preds,
               const float4* __restrict__ targs,
               float* __restrict__ pr, float* __restrict__ pt,
               float* __restrict__ pp) {
    const int row = blockIdx.x;          // one row per block
    const int tid = threadIdx.x;
    const float4* prow = preds + row * (NCOLS / 4);
    const float4* trow = targs + row * (NCOLS / 4);

    // Issue ALL 12 dwordx4 loads back-to-back, then pin every component live
    // so the compiler cannot sink loads into the compute (round-2 failure:
    // VGPR=32 proved loads were serialized one vmcnt(0) at a time).
    float4 p[CHUNKS], t[CHUNKS];
#pragma unroll
    for (int k = 0; k < CHUNKS; ++k) p[k] = prow[tid + TPB * k];
#pragma unroll
    for (int k = 0; k < CHUNKS; ++k) t[k] = trow[tid + TPB * k];
    asm volatile("" :
        "+v"(p[0].x),"+v"(p[0].y),"+v"(p[0].z),"+v"(p[0].w),
        "+v"(p[1].x),"+v"(p[1].y),"+v"(p[1].z),"+v"(p[1].w),
        "+v"(p[2].x),"+v"(p[2].y),"+v"(p[2].z),"+v"(p[2].w),
        "+v"(p[3].x),"+v"(p[3].y),"+v"(p[3].z),"+v"(p[3].w),
        "+v"(p[4].x),"+v"(p[4].y),"+v"(p[4].z),"+v"(p[4].w),
        "+v"(p[5].x),"+v"(p[5].y),"+v"(p[5].z),"+v"(p[5].w));
    asm volatile("" :
        "+v"(t[0].x),"+v"(t[0].y),"+v"(t[0].z),"+v"(t[0].w),
        "+v"(t[1].x),"+v"(t[1].y),"+v"(t[1].z),"+v"(t[1].w),
        "+v"(t[2].x),"+v"(t[2].y),"+v"(t[2].z),"+v"(t[2].w),
        "+v"(t[3].x),"+v"(t[3].y),"+v"(t[3].z),"+v"(t[3].w),
        "+v"(t[4].x),"+v"(t[4].y),"+v"(t[4].z),"+v"(t[4].w),
        "+v"(t[5].x),"+v"(t[5].y),"+v"(t[5].z),"+v"(t[5].w));

    const int tidm3 = tid % 3;           // col%3 = (tid+k+j)%3  (4≡1, 1024≡1 mod 3)
    float asum = 0.f, psum = 0.f;
#pragma unroll
    for (int k = 0; k < CHUNKS; ++k) {
        const float ps[4] = {p[k].x, p[k].y, p[k].z, p[k].w};
        const float ts[4] = {t[k].x, t[k].y, t[k].z, t[k].w};
#pragma unroll
        for (int j = 0; j < 4; ++j) {
            const float e = __expf(-ps[j]);
            const float s = __builtin_amdgcn_rcpf(1.0f + e);   // sigmoid
            const float x = s - ts[j];
            const float a = fabsf(x);
            asum += a;
            if (k < 4) {                 // col<4096 ⟺ k<4 (compile-time)
                const float d = fminf(a, fminf(fabsf(x - 1.f), fabsf(x + 1.f)));
                const int want = ((2 - k - j) % 3 + 3) % 3;    // compile-time
                psum += (tidm3 == want) ? d : 0.f;
            }
        }
    }

    // 64-lane wave reduction, then cross-wave via LDS
#pragma unroll
    for (int off = 32; off > 0; off >>= 1) {
        asum += __shfl_down(asum, off);
        psum += __shfl_down(psum, off);
    }
    __shared__ float la[4], lp[4];
    const int wave = tid >> 6, lane = tid & 63;
    if (lane == 0) { la[wave] = asum; lp[wave] = psum; }
    __syncthreads();

    if (tid == 0) {
        const float ba = la[0] + la[1] + la[2] + la[3];
        const float bp = lp[0] + lp[1] + lp[2] + lp[3];
        const int rm = row % 3;
        pr[row] = (rm == 0) ? ba : 0.f;  // every slot written every call:
        pt[row] = (rm == 1) ? ba : 0.f;  // no memset needed, no stale ws state
        pp[row] = bp;
    }
}

__global__ void __launch_bounds__(1024)
spherical_final(const float* __restrict__ pr, const float* __restrict__ pt,
                const float* __restrict__ pp, float* __restrict__ out) {
    const int tid = threadIdx.x;
    double sr = 0.0, st = 0.0, sp = 0.0;
    for (int i = tid; i < NROWS; i += 1024) {   // fixed order -> deterministic
        sr += (double)pr[i]; st += (double)pt[i]; sp += (double)pp[i];
    }
#pragma unroll
    for (int off = 32; off > 0; off >>= 1) {
        sr += __shfl_down(sr, off);
        st += __shfl_down(st, off);
        sp += __shfl_down(sp, off);
    }
    __shared__ double dr[16], dt[16], dp[16];
    const int wave = tid >> 6, lane = tid & 63;
    if (lane == 0) { dr[wave] = sr; dt[wave] = st; dp[wave] = sp; }
    __syncthreads();
    if (tid == 0) {
        double r = 0.0, t = 0.0, p = 0.0;
#pragma unroll
        for (int w = 0; w < 16; ++w) { r += dr[w]; t += dt[w]; p += dp[w]; }
        r /= 1366.0 * 6144.0;
        t /= 1365.0 * 6144.0;
        p /= 4096.0 * 2048.0;
        out[0] = (float)(r + t + p);
        out[1] = (float)r;
        out[2] = (float)t;
        out[3] = (float)p;
    }
}

extern "C" void kernel_launch(void* const* d_in, const int* in_sizes, int n_in,
                              void* d_out, int out_size, void* d_ws, size_t ws_size,
                              hipStream_t stream) {
    const float4* preds = (const float4*)d_in[0];
    const float4* targs = (const float4*)d_in[1];
    float* pr = (float*)d_ws;        // 4096 floats
    float* pt = pr + NROWS;          // 4096 floats
    float* pp = pt + NROWS;          // 4096 floats  (48 KB total)

    spherical_main<<<dim3(NROWS), dim3(TPB), 0, stream>>>(preds, targs, pr, pt, pp);
    spherical_final<<<dim3(1), dim3(1024), 0, stream>>>(pr, pt, pp, (float*)d_out);
}

// Round 4
// 34.939 us; speedup vs baseline: 3.1421x; 1.0894x over previous
//
#include <hip/hip_runtime.h>

#define NROWS 4096
#define NCOLS 6144
#define TPB   256
#define NBLK  (NROWS / 2)   // 2048 blocks, 2 rows each

// Semantics (verbatim from reference):
//   r_loss  = mean |sigmoid(p)-t| over rows ≡0 mod 3  (1366 rows × 6144 cols)
//   t_loss  = mean |sigmoid(p)-t| over rows ≡1 mod 3  (1365 rows × 6144 cols)
//   phi     = sum of circular dist over ALL rows, cols with col%3==2 AND col<4096
//             (b=4096 used as the column bound!), divided by 4096*2048.
// Rows ≡2 mod 3 only contribute phi (cols<4096) -> load only chunks k<4 (saves 11% traffic).

template<int KCH>
__device__ __forceinline__ void loadRow(const float4* __restrict__ prow,
                                        const float4* __restrict__ trow,
                                        int tid, float4 (&p)[KCH], float4 (&t)[KCH]) {
#pragma unroll
    for (int k = 0; k < KCH; ++k) p[k] = prow[tid + TPB * k];
#pragma unroll
    for (int k = 0; k < KCH; ++k) t[k] = trow[tid + TPB * k];
}

__device__ __forceinline__ void pin6(float4 (&a)[6]) {
    asm volatile("" :
        "+v"(a[0].x),"+v"(a[0].y),"+v"(a[0].z),"+v"(a[0].w),
        "+v"(a[1].x),"+v"(a[1].y),"+v"(a[1].z),"+v"(a[1].w),
        "+v"(a[2].x),"+v"(a[2].y),"+v"(a[2].z),"+v"(a[2].w),
        "+v"(a[3].x),"+v"(a[3].y),"+v"(a[3].z),"+v"(a[3].w),
        "+v"(a[4].x),"+v"(a[4].y),"+v"(a[4].z),"+v"(a[4].w),
        "+v"(a[5].x),"+v"(a[5].y),"+v"(a[5].z),"+v"(a[5].w));
}
__device__ __forceinline__ void pin4(float4 (&a)[4]) {
    asm volatile("" :
        "+v"(a[0].x),"+v"(a[0].y),"+v"(a[0].z),"+v"(a[0].w),
        "+v"(a[1].x),"+v"(a[1].y),"+v"(a[1].z),"+v"(a[1].w),
        "+v"(a[2].x),"+v"(a[2].y),"+v"(a[2].z),"+v"(a[2].w),
        "+v"(a[3].x),"+v"(a[3].y),"+v"(a[3].z),"+v"(a[3].w));
}

// BUCKET: 0 = accumulate |sigmoid-t| into asum; 2 = phi-only (asum untouched)
template<int KCH, int BUCKET>
__device__ __forceinline__ void computeRow(const float4 (&p)[KCH], const float4 (&t)[KCH],
                                           int tidm3, float& asum, float& psum) {
#pragma unroll
    for (int k = 0; k < KCH; ++k) {
        const float ps4[4] = {p[k].x, p[k].y, p[k].z, p[k].w};
        const float ts4[4] = {t[k].x, t[k].y, t[k].z, t[k].w};
#pragma unroll
        for (int j = 0; j < 4; ++j) {
            const float e = __expf(-ps4[j]);
            const float s = __builtin_amdgcn_rcpf(1.0f + e);   // sigmoid
            const float x = s - ts4[j];
            const float a = fabsf(x);
            if (BUCKET != 2) asum += a;
            if (k < 4) {   // col < 4096 ⟺ k < 4 (compile-time)
                const float d = fminf(a, fminf(fabsf(x - 1.f), fabsf(x + 1.f)));
                const int want = ((2 - k - j) % 3 + 3) % 3;    // col%3==2 ⟺ tid%3==want
                psum += (tidm3 == want) ? d : 0.f;
            }
        }
    }
}

__global__ void __launch_bounds__(256)
spherical_main(const float4* __restrict__ preds,
               const float4* __restrict__ targs,
               float* __restrict__ pr, float* __restrict__ pt,
               float* __restrict__ pp) {
    const int b   = blockIdx.x;
    const int tid = threadIdx.x;
    const int r0  = 2 * b, r1 = 2 * b + 1;
    const float4* p0 = preds + r0 * (NCOLS / 4);
    const float4* t0 = targs + r0 * (NCOLS / 4);
    const float4* p1 = preds + r1 * (NCOLS / 4);
    const float4* t1 = targs + r1 * (NCOLS / 4);
    const int tidm3 = tid % 3;
    const int kind  = b % 3;   // rows mod 3: 0->(0,1)  1->(2,0)  2->(1,2)  (wave-uniform)

    float ar = 0.f, at = 0.f, ps = 0.f;

    if (kind == 0) {                       // (rm0 -> r, rm1 -> t): 24 loads in flight
        float4 pa[6], ta[6], pb[6], tb[6];
        loadRow<6>(p0, t0, tid, pa, ta);
        loadRow<6>(p1, t1, tid, pb, tb);
        pin6(pa); pin6(ta); pin6(pb); pin6(tb);
        computeRow<6, 0>(pa, ta, tidm3, ar, ps);
        computeRow<6, 0>(pb, tb, tidm3, at, ps);
    } else if (kind == 1) {                // (rm2 phi-only, rm0 -> r): 20 loads
        float4 pa[4], ta[4], pb[6], tb[6];
        loadRow<4>(p0, t0, tid, pa, ta);
        loadRow<6>(p1, t1, tid, pb, tb);
        pin4(pa); pin4(ta); pin6(pb); pin6(tb);
        computeRow<4, 2>(pa, ta, tidm3, ar, ps);
        computeRow<6, 0>(pb, tb, tidm3, ar, ps);
    } else {                               // (rm1 -> t, rm2 phi-only): 20 loads
        float4 pa[6], ta[6], pb[4], tb[4];
        loadRow<6>(p0, t0, tid, pa, ta);
        loadRow<4>(p1, t1, tid, pb, tb);
        pin6(pa); pin6(ta); pin4(pb); pin4(tb);
        computeRow<6, 0>(pa, ta, tidm3, at, ps);
        computeRow<4, 2>(pb, tb, tidm3, at, ps);
    }

    // 64-lane wave reduction of the 3 partials, then cross-wave via LDS
#pragma unroll
    for (int off = 32; off > 0; off >>= 1) {
        ar += __shfl_down(ar, off);
        at += __shfl_down(at, off);
        ps += __shfl_down(ps, off);
    }
    __shared__ float lr[4], lt[4], lp[4];
    const int wave = tid >> 6, lane = tid & 63;
    if (lane == 0) { lr[wave] = ar; lt[wave] = at; lp[wave] = ps; }
    __syncthreads();
    if (tid == 0) {
        pr[b] = lr[0] + lr[1] + lr[2] + lr[3];   // every slot written every call
        pt[b] = lt[0] + lt[1] + lt[2] + lt[3];
        pp[b] = lp[0] + lp[1] + lp[2] + lp[3];
    }
}

__global__ void __launch_bounds__(1024)
spherical_final(const float* __restrict__ pr, const float* __restrict__ pt,
                const float* __restrict__ pp, float* __restrict__ out) {
    const int tid = threadIdx.x;
    double sr = 0.0, st = 0.0, sp = 0.0;
    for (int i = tid; i < NBLK; i += 1024) {    // fixed order -> deterministic
        sr += (double)pr[i]; st += (double)pt[i]; sp += (double)pp[i];
    }
#pragma unroll
    for (int off = 32; off > 0; off >>= 1) {
        sr += __shfl_down(sr, off);
        st += __shfl_down(st, off);
        sp += __shfl_down(sp, off);
    }
    __shared__ double dr[16], dt[16], dp[16];
    const int wave = tid >> 6, lane = tid & 63;
    if (lane == 0) { dr[wave] = sr; dt[wave] = st; dp[wave] = sp; }
    __syncthreads();
    if (tid == 0) {
        double r = 0.0, t = 0.0, p = 0.0;
#pragma unroll
        for (int w = 0; w < 16; ++w) { r += dr[w]; t += dt[w]; p += dp[w]; }
        r /= 1366.0 * 6144.0;
        t /= 1365.0 * 6144.0;
        p /= 4096.0 * 2048.0;
        out[0] = (float)(r + t + p);
        out[1] = (float)r;
        out[2] = (float)t;
        out[3] = (float)p;
    }
}

extern "C" void kernel_launch(void* const* d_in, const int* in_sizes, int n_in,
                              void* d_out, int out_size, void* d_ws, size_t ws_size,
                              hipStream_t stream) {
    const float4* preds = (const float4*)d_in[0];
    const float4* targs = (const float4*)d_in[1];
    float* pr = (float*)d_ws;        // 2048 floats
    float* pt = pr + NBLK;           // 2048 floats
    float* pp = pt + NBLK;           // 2048 floats (24 KB total)

    spherical_main<<<dim3(NBLK), dim3(TPB), 0, stream>>>(preds, targs, pr, pt, pp);
    spherical_final<<<dim3(1), dim3(1024), 0, stream>>>(pr, pt, pp, (float*)d_out);
}

// Round 5
// 34.131 us; speedup vs baseline: 3.2165x; 1.0237x over previous
//
#include <hip/hip_runtime.h>

#define NROWS 4096
#define NCOLS 6144
#define TPB   256
#define NBLK  (NROWS / 2)   // 2048 blocks, 2 rows each

typedef float f32x4 __attribute__((ext_vector_type(4)));

// Semantics (verbatim from reference):
//   r_loss  = mean |sigmoid(p)-t| over rows ≡0 mod 3  (1366 rows × 6144 cols)
//   t_loss  = mean |sigmoid(p)-t| over rows ≡1 mod 3  (1365 rows × 6144 cols)
//   phi     = sum over ALL rows, cols with col%3==2 AND col<4096 of
//             min(|x|,|x-1|,|x+1|), x = sigmoid(p)-t; divided by 4096*2048.
//             Since x∈[-1,1]: min(|x|,|x-1|,|x+1|) == min(|x|, 1-|x|).
// Rows ≡2 mod 3 contribute only phi (cols<4096) -> load only chunks k<4.
//
// Pipeline: all loads issued via asm volatile (cannot be sunk), consumed with
// counted s_waitcnt vmcnt(N) so chunk-c compute overlaps the remaining
// in-flight loads (round-4 failure: pinned wait-all serialized transfer
// then compute).

#define GLOAD(dst, ptr) \
    asm volatile("global_load_dwordx4 %0, %1, off" : "=v"(dst) : "v"(ptr))
#define WAITV(N) do { \
    asm volatile("s_waitcnt vmcnt(" #N ")"); \
    __builtin_amdgcn_sched_barrier(0); } while (0)

#define ISSUE2(P, T, pb, tb, k) GLOAD(P[k], (pb) + (k)*TPB); GLOAD(T[k], (tb) + (k)*TPB)
#define ISSUE_ROW6(P, T, pb, tb) \
    ISSUE2(P,T,pb,tb,0); ISSUE2(P,T,pb,tb,1); ISSUE2(P,T,pb,tb,2); \
    ISSUE2(P,T,pb,tb,3); ISSUE2(P,T,pb,tb,4); ISSUE2(P,T,pb,tb,5)
#define ISSUE_ROW4(P, T, pb, tb) \
    ISSUE2(P,T,pb,tb,0); ISSUE2(P,T,pb,tb,1); ISSUE2(P,T,pb,tb,2); ISSUE2(P,T,pb,tb,3)

// BKT 0: accumulate |sigmoid-t| into asum (+phi if K<4); BKT 2: phi only.
template<int K, int BKT>
__device__ __forceinline__ void chunk(f32x4 p, f32x4 t, int tidm3,
                                      float& asum, float& psum) {
#pragma unroll
    for (int j = 0; j < 4; ++j) {
        const float e = __expf(-p[j]);
        const float s = __builtin_amdgcn_rcpf(1.0f + e);   // sigmoid
        const float x = s - t[j];
        const float a = fabsf(x);
        if (BKT != 2) asum += a;
        if (K < 4) {                       // col < 4096 ⟺ k < 4 (compile-time)
            const float d = fminf(a, 1.0f - a);            // circular dist
            const int want = ((2 - K - j) % 3 + 3) % 3;    // col%3==2 ⟺ tid%3==want
            psum += (tidm3 == want) ? d : 0.0f;
        }
    }
}

__global__ void __launch_bounds__(256)
spherical_main(const f32x4* __restrict__ preds,
               const f32x4* __restrict__ targs,
               float* __restrict__ pr, float* __restrict__ pt,
               float* __restrict__ pp) {
    const int b   = blockIdx.x;
    const int tid = threadIdx.x;
    const f32x4* pA = preds + (size_t)(2 * b) * (NCOLS / 4) + tid;
    const f32x4* tA = targs + (size_t)(2 * b) * (NCOLS / 4) + tid;
    const f32x4* pB = pA + (NCOLS / 4);
    const f32x4* tB = tA + (NCOLS / 4);
    const int tidm3 = tid % 3;
    const int kind  = b % 3;   // rows mod 3: 0->(0,1)  1->(2,0)  2->(1,2)  uniform

    float ar = 0.f, at = 0.f, ps = 0.f;

    if (kind == 0) {                       // rowA -> r, rowB -> t : 24 loads
        f32x4 pa[6], ta[6], pb_[6], tb_[6];
        ISSUE_ROW6(pa, ta, pA, tA);
        ISSUE_ROW6(pb_, tb_, pB, tB);
        WAITV(22); chunk<0,0>(pa[0], ta[0], tidm3, ar, ps);
        WAITV(20); chunk<1,0>(pa[1], ta[1], tidm3, ar, ps);
        WAITV(18); chunk<2,0>(pa[2], ta[2], tidm3, ar, ps);
        WAITV(16); chunk<3,0>(pa[3], ta[3], tidm3, ar, ps);
        WAITV(14); chunk<4,0>(pa[4], ta[4], tidm3, ar, ps);
        WAITV(12); chunk<5,0>(pa[5], ta[5], tidm3, ar, ps);
        WAITV(10); chunk<0,0>(pb_[0], tb_[0], tidm3, at, ps);
        WAITV(8);  chunk<1,0>(pb_[1], tb_[1], tidm3, at, ps);
        WAITV(6);  chunk<2,0>(pb_[2], tb_[2], tidm3, at, ps);
        WAITV(4);  chunk<3,0>(pb_[3], tb_[3], tidm3, at, ps);
        WAITV(2);  chunk<4,0>(pb_[4], tb_[4], tidm3, at, ps);
        WAITV(0);  chunk<5,0>(pb_[5], tb_[5], tidm3, at, ps);
    } else if (kind == 1) {                // rowA phi-only, rowB -> r : 20 loads
        f32x4 pa[4], ta[4], pb_[6], tb_[6];
        ISSUE_ROW4(pa, ta, pA, tA);
        ISSUE_ROW6(pb_, tb_, pB, tB);
        WAITV(18); chunk<0,2>(pa[0], ta[0], tidm3, ar, ps);
        WAITV(16); chunk<1,2>(pa[1], ta[1], tidm3, ar, ps);
        WAITV(14); chunk<2,2>(pa[2], ta[2], tidm3, ar, ps);
        WAITV(12); chunk<3,2>(pa[3], ta[3], tidm3, ar, ps);
        WAITV(10); chunk<0,0>(pb_[0], tb_[0], tidm3, ar, ps);
        WAITV(8);  chunk<1,0>(pb_[1], tb_[1], tidm3, ar, ps);
        WAITV(6);  chunk<2,0>(pb_[2], tb_[2], tidm3, ar, ps);
        WAITV(4);  chunk<3,0>(pb_[3], tb_[3], tidm3, ar, ps);
        WAITV(2);  chunk<4,0>(pb_[4], tb_[4], tidm3, ar, ps);
        WAITV(0);  chunk<5,0>(pb_[5], tb_[5], tidm3, ar, ps);
    } else {                               // rowA -> t, rowB phi-only : 20 loads
        f32x4 pa[6], ta[6], pb_[4], tb_[4];
        ISSUE_ROW6(pa, ta, pA, tA);
        ISSUE_ROW4(pb_, tb_, pB, tB);
        WAITV(18); chunk<0,0>(pa[0], ta[0], tidm3, at, ps);
        WAITV(16); chunk<1,0>(pa[1], ta[1], tidm3, at, ps);
        WAITV(14); chunk<2,0>(pa[2], ta[2], tidm3, at, ps);
        WAITV(12); chunk<3,0>(pa[3], ta[3], tidm3, at, ps);
        WAITV(10); chunk<4,0>(pa[4], ta[4], tidm3, at, ps);
        WAITV(8);  chunk<5,0>(pa[5], ta[5], tidm3, at, ps);
        WAITV(6);  chunk<0,2>(pb_[0], tb_[0], tidm3, at, ps);
        WAITV(4);  chunk<1,2>(pb_[1], tb_[1], tidm3, at, ps);
        WAITV(2);  chunk<2,2>(pb_[2], tb_[2], tidm3, at, ps);
        WAITV(0);  chunk<3,2>(pb_[3], tb_[3], tidm3, at, ps);
    }

    // 64-lane wave reduction of the 3 partials, then cross-wave via LDS
#pragma unroll
    for (int off = 32; off > 0; off >>= 1) {
        ar += __shfl_down(ar, off);
        at += __shfl_down(at, off);
        ps += __shfl_down(ps, off);
    }
    __shared__ float lr[4], lt[4], lp[4];
    const int wave = tid >> 6, lane = tid & 63;
    if (lane == 0) { lr[wave] = ar; lt[wave] = at; lp[wave] = ps; }
    __syncthreads();
    if (tid == 0) {
        pr[b] = lr[0] + lr[1] + lr[2] + lr[3];   // every slot written every call
        pt[b] = lt[0] + lt[1] + lt[2] + lt[3];
        pp[b] = lp[0] + lp[1] + lp[2] + lp[3];
    }
}

__global__ void __launch_bounds__(1024)
spherical_final(const float* __restrict__ pr, const float* __restrict__ pt,
                const float* __restrict__ pp, float* __restrict__ out) {
    const int tid = threadIdx.x;
    double sr = 0.0, st = 0.0, sp = 0.0;
    for (int i = tid; i < NBLK; i += 1024) {    // fixed order -> deterministic
        sr += (double)pr[i]; st += (double)pt[i]; sp += (double)pp[i];
    }
#pragma unroll
    for (int off = 32; off > 0; off >>= 1) {
        sr += __shfl_down(sr, off);
        st += __shfl_down(st, off);
        sp += __shfl_down(sp, off);
    }
    __shared__ double dr[16], dt[16], dp[16];
    const int wave = tid >> 6, lane = tid & 63;
    if (lane == 0) { dr[wave] = sr; dt[wave] = st; dp[wave] = sp; }
    __syncthreads();
    if (tid == 0) {
        double r = 0.0, t = 0.0, p = 0.0;
#pragma unroll
        for (int w = 0; w < 16; ++w) { r += dr[w]; t += dt[w]; p += dp[w]; }
        r /= 1366.0 * 6144.0;
        t /= 1365.0 * 6144.0;
        p /= 4096.0 * 2048.0;
        out[0] = (float)(r + t + p);
        out[1] = (float)r;
        out[2] = (float)t;
        out[3] = (float)p;
    }
}

extern "C" void kernel_launch(void* const* d_in, const int* in_sizes, int n_in,
                              void* d_out, int out_size, void* d_ws, size_t ws_size,
                              hipStream_t stream) {
    const f32x4* preds = (const f32x4*)d_in[0];
    const f32x4* targs = (const f32x4*)d_in[1];
    float* pr = (float*)d_ws;        // 2048 floats
    float* pt = pr + NBLK;           // 2048 floats
    float* pp = pt + NBLK;           // 2048 floats (24 KB total)

    spherical_main<<<dim3(NBLK), dim3(TPB), 0, stream>>>(preds, targs, pr, pt, pp);
    spherical_final<<<dim3(1), dim3(1024), 0, stream>>>(pr, pt, pp, (float*)d_out);
}